// Round 8
// baseline (132.195 us; speedup 1.0000x reference)
//
#include <hip/hip_runtime.h>
#include <math.h>

#define NN 4096
#define DD 512
#define MARGINF 1.0f
#define NCLS 64
#define MAXM 160
#define TRI (MAXM * (MAXM - 1) / 2)   // 12720
#define NBLK 2080                     // 64*65/2 triangular 64-tiles
#define NSLICE 4                      // pair2 blocks per class

typedef __attribute__((ext_vector_type(8))) short bf16x8;  // 8 bf16 (4 VGPRs)
typedef __attribute__((ext_vector_type(4))) float f32x4;   // 4 fp32 acc

// ws layout (float indices):
#define WS_SQ   0         // float[4096] ||x_i||^2
#define WS_NS   4096      // float[4096] neg_sum
#define WS_LOSS 8192      // float[1] sum hinge^2
#define WS_CTR  8193      // uint[1] pair2 completion counter
#define WS_LENP 8194      // float[1] sum over classes mc*(mc-1)
#define WS_RK   8320      // int[4096] rank within class (atomic-free)
#define WS_MEM  12416     // int[64*160] class member lists (rank-indexed)
#define WS_XF   32768     // ushort[4096*512] FRAGMENT-MAJOR bf16 X (4 MB)
                          //   frag(r16,kb) = 1KB at short-off (r16*16+kb)*512;
                          //   element lane*8+e  (lane=q*16+m, e=k&7)
#define WS_PD   1081344   // float[64*TRI] positive-pair distances

__device__ __forceinline__ unsigned short f2bf(float f) {
    unsigned u = __float_as_uint(f);
    u += 0x7fffu + ((u >> 16) & 1u);   // round-to-nearest-even
    return (unsigned short)(u >> 16);
}

// Row norms + fragment-major bf16 conversion + ATOMIC-FREE class ranks.
__global__ __launch_bounds__(256) void prep_kernel(const float* __restrict__ X,
                                                   const int* __restrict__ tgt,
                                                   float* __restrict__ ws) {
    __shared__ int tg[NN];   // 16 KB
    const int tid = threadIdx.x;
    for (int j = tid; j < NN; j += 256) tg[j] = tgt[j];

    const int wv = tid >> 6, lane = tid & 63;
    const int row = blockIdx.x * 4 + wv;
    const float4* xr = (const float4*)(X + (size_t)row * DD);
    float4 a = xr[2 * lane], b = xr[2 * lane + 1];
    float s = a.x * a.x + a.y * a.y + a.z * a.z + a.w * a.w
            + b.x * b.x + b.y * b.y + b.z * b.z + b.w * b.w;
#pragma unroll
    for (int off = 32; off; off >>= 1) s += __shfl_down(s, off, 64);

    ushort4 pa = {f2bf(a.x), f2bf(a.y), f2bf(a.z), f2bf(a.w)};
    ushort4 pb = {f2bf(b.x), f2bf(b.y), f2bf(b.z), f2bf(b.w)};
    const int r16 = row >> 4, m = row & 15;
    const int kb = lane >> 2, q = lane & 3;
    ushort4* dst = (ushort4*)((unsigned short*)(ws + WS_XF)
                              + ((size_t)(r16 * 16 + kb) * 64 + q * 16 + m) * 8);
    dst[0] = pa;
    dst[1] = pb;

    __syncthreads();
    const int myc = tg[row];
    int cnt = 0;
    for (int j = lane; j < row; j += 64) cnt += (tg[j] == myc) ? 1 : 0;
#pragma unroll
    for (int off = 32; off; off >>= 1) cnt += __shfl_down(cnt, off, 64);
    if (lane == 0) {
        ws[WS_SQ + row] = s;
        ws[WS_NS + row] = 0.0f;
        ((int*)(ws + WS_RK))[row] = cnt;
        if (cnt < MAXM) ((int*)(ws + WS_MEM))[myc * MAXM + cnt] = row;
    }
    if (blockIdx.x == 0 && tid == 0) {
        ws[WS_LOSS] = 0.0f;
        ((unsigned*)ws)[WS_CTR] = 0u;
        ws[WS_LENP] = 0.0f;
    }
}

// Gram via bf16 MFMA. ONE WAVE PER BLOCK, 64x64 tile per wave, ZERO barriers.
// The wave DMAs its own 8 frags/chunk (global_load_lds w16) into a PRIVATE
// 3-buffer LDS ring (24 KB -> 6 blocks/CU), ordered only by its own counted
// s_waitcnt vmcnt(8) (chunk t+2 in flight across the chunk boundary; wait
// covers chunk t+1 issued a full chunk earlier). Removes R7's 4-wave barrier
// coupling (16 barriers x 2 waits per block) entirely. ds:MFMA = 8:16 (half
// of R7's per-MFMA LDS reads). Traffic unchanged: 128 KB/tile = 266 MB,
// L2-resident per XCD after the 2080=8*260 swizzle; fetch-bound floor
// ~7.7 us/CU. Buffer reuse race-free: single-wave program order + the
// memory-clobber waitcnt pins ds_reads (before) and DMAs (after).
__global__ __launch_bounds__(64) void negsum_kernel(const int* __restrict__ tgt,
                                                    float* __restrict__ ws) {
    __shared__ unsigned short lds[3][8][512];   // [buf][frag: 0-3 A, 4-7 B] 24 KB
    // XCD-chunked bijective swizzle: 2080 = 8 * 260.
    const int bidx = (blockIdx.x & 7) * 260 + (blockIdx.x >> 3);
    int bj = (int)((sqrtf(8.0f * (float)bidx + 1.0f) - 1.0f) * 0.5f);
    while (bj * (bj + 1) / 2 > bidx) --bj;
    while ((bj + 1) * (bj + 2) / 2 <= bidx) ++bj;
    const int bi = bidx - bj * (bj + 1) / 2;   // bi <= bj
    const int i0 = bi * 64, j0 = bj * 64;

    const int lane = threadIdx.x;              // 64-thread block = 1 wave
    const int m_ = lane & 15, q = lane >> 4;
    const unsigned short* Xf = (const unsigned short*)(ws + WS_XF);
    const int air0 = i0 >> 4, bjr0 = j0 >> 4;

    int fr16[8];
#pragma unroll
    for (int s = 0; s < 8; ++s) fr16[s] = (s < 4) ? (air0 + s) : (bjr0 + (s - 4));

#define DMA_CHUNK(kb_, buf_)                                                   \
    {                                                                          \
        _Pragma("unroll")                                                      \
        for (int s = 0; s < 8; ++s) {                                          \
            const unsigned short* gp =                                         \
                Xf + ((size_t)fr16[s] * 16 + (kb_)) * 512 + lane * 8;          \
            __builtin_amdgcn_global_load_lds(                                  \
                (const __attribute__((address_space(1))) int*)gp,              \
                (__attribute__((address_space(3))) int*)(&lds[buf_][s][0]),    \
                16, 0, 0);                                                     \
        }                                                                      \
    }

    f32x4 acc[4][4] = {};

    // prologue: chunks 0,1 in flight (16 outstanding); wait to 8 -> chunk 0 ready
    DMA_CHUNK(0, 0)
    DMA_CHUNK(1, 1)
    asm volatile("s_waitcnt vmcnt(8)" ::: "memory");

#pragma unroll
    for (int t = 0; t < 16; ++t) {
        const int cur = t % 3;
        if (t < 14) DMA_CHUNK(t + 2, (t + 2) % 3)
        bf16x8 af[4], bf[4];
#pragma unroll
        for (int u = 0; u < 4; ++u)
            af[u] = *(const bf16x8*)&lds[cur][u][lane * 8];
#pragma unroll
        for (int v = 0; v < 4; ++v)
            bf[v] = *(const bf16x8*)&lds[cur][4 + v][lane * 8];
#pragma unroll
        for (int u = 0; u < 4; ++u)
#pragma unroll
            for (int v = 0; v < 4; ++v)
                acc[u][v] = __builtin_amdgcn_mfma_f32_16x16x32_bf16(
                    af[u], bf[v], acc[u][v], 0, 0, 0);
        if (t < 14) {
            // chunk t+1 ready (t+2 stays in flight); lgkmcnt(0) guarantees this
            // chunk's ds_reads retired before next iter's DMA rewrites buf[cur+2]
            asm volatile("s_waitcnt vmcnt(8) lgkmcnt(0)" ::: "memory");
        } else if (t == 14) {
            asm volatile("s_waitcnt vmcnt(0) lgkmcnt(0)" ::: "memory");
        }
    }
#undef DMA_CHUNK

    // epilogue: C/D map col=lane&15, row=(lane>>4)*4+reg
    const float* sq = ws + WS_SQ;
    float* ns = ws + WS_NS;
    const int* rk = (const int*)(ws + WS_RK);
    float* posd = ws + WS_PD;
    float sjv[4]; int tjv[4], jv[4];
#pragma unroll
    for (int v = 0; v < 4; ++v) {
        int j = j0 + v * 16 + m_;
        jv[v] = j;
        sjv[v] = sq[j];
        tjv[v] = tgt[j];
    }
    float colp[4] = {0.0f, 0.0f, 0.0f, 0.0f};
#pragma unroll
    for (int u = 0; u < 4; ++u) {
#pragma unroll
        for (int r = 0; r < 4; ++r) {
            const int i = i0 + u * 16 + q * 4 + r;
            const float si = sq[i];
            const int ti = tgt[i];
            float rp = 0.0f;
#pragma unroll
            for (int v = 0; v < 4; ++v) {
                float d2 = si + sjv[v] - 2.0f * acc[u][v][r];
                float dist = d2 > 0.0f ? sqrtf(d2) : 0.0f;
                if (tjv[v] != ti) {
                    float e = __expf(MARGINF - dist);
                    rp += e;
                    colp[v] += e;
                } else if (i < jv[v]) {
                    int ra = rk[i], rb = rk[jv[v]];
                    if (ra < MAXM && rb < MAXM) {
                        int hi = ra > rb ? ra : rb;
                        int lo = ra > rb ? rb : ra;
                        posd[ti * TRI + hi * (hi - 1) / 2 + lo] = dist;
                    }
                }
            }
            rp += __shfl_xor(rp, 1, 64);
            rp += __shfl_xor(rp, 2, 64);
            rp += __shfl_xor(rp, 4, 64);
            rp += __shfl_xor(rp, 8, 64);
            if (m_ == 0) atomicAdd(&ns[i], rp);
        }
    }
    if (bi != bj) {   // symmetric contribution: G[j][i] == G[i][j]
#pragma unroll
        for (int v = 0; v < 4; ++v) {
            float cp = colp[v];
            cp += __shfl_xor(cp, 16, 64);
            cp += __shfl_xor(cp, 32, 64);
            if (q == 0) atomicAdd(&ns[jv[v]], cp);
        }
    }
}

// Positive pairs from stored distances; NSLICE blocks per class for occupancy;
// last block finalizes out = loss / len_p.
__global__ __launch_bounds__(256) void pair2_kernel(const int* __restrict__ tgt,
                                                    float* __restrict__ ws,
                                                    float* __restrict__ out) {
    __shared__ float wsum[4];
    __shared__ int csum[4];
    __shared__ bool last;
    const int c = blockIdx.x >> 2;
    const int sl = blockIdx.x & 3;
    const int tid = threadIdx.x;
    const int wv = tid >> 6, lane = tid & 63;

    int ccount = 0;
    for (int j = tid; j < NN; j += 256) ccount += (tgt[j] == c) ? 1 : 0;
#pragma unroll
    for (int off = 32; off; off >>= 1) ccount += __shfl_down(ccount, off, 64);
    if (lane == 0) csum[wv] = ccount;
    __syncthreads();
    int mc = csum[0] + csum[1] + csum[2] + csum[3];
    if (mc > MAXM) mc = MAXM;
    const int P = mc * (mc - 1) / 2;

    const int* mem = (const int*)(ws + WS_MEM) + c * MAXM;
    const float* pd = ws + WS_PD + c * TRI;
    const float* ns = ws + WS_NS;
    float lsum = 0.0f;
    for (int p = tid + sl * 256; p < P; p += 256 * NSLICE) {
        int b = (int)((1.0f + sqrtf(1.0f + 8.0f * (float)p)) * 0.5f);
        while (b * (b - 1) / 2 > p) --b;
        while ((b + 1) * b / 2 <= p) ++b;
        const int a = p - b * (b - 1) / 2;
        const float dist = pd[b * (b - 1) / 2 + a];
        const int i = mem[a], j = mem[b];
        float J = __logf(ns[i] + ns[j]) + dist;
        float h = fmaxf(J, 0.0f);
        lsum += h * h;
    }
#pragma unroll
    for (int off = 32; off; off >>= 1) lsum += __shfl_xor(lsum, off, 64);
    if (lane == 0) wsum[wv] = lsum;
    __syncthreads();
    if (tid == 0) {
        float s = wsum[0] + wsum[1] + wsum[2] + wsum[3];
        if (s != 0.0f) atomicAdd(&ws[WS_LOSS], s);
        if (sl == 0) atomicAdd(&ws[WS_LENP], (float)(mc * (mc - 1)));
        __threadfence();
        unsigned d = atomicAdd((unsigned*)ws + WS_CTR, 1u);
        last = (d == NCLS * NSLICE - 1);
    }
    __syncthreads();
    if (last && tid == 0) {
        float total = atomicAdd(&ws[WS_LOSS], 0.0f);   // device-scope reads
        float lp = atomicAdd(&ws[WS_LENP], 0.0f);
        out[0] = total / lp;
    }
}

extern "C" void kernel_launch(void* const* d_in, const int* in_sizes, int n_in,
                              void* d_out, int out_size, void* d_ws, size_t ws_size,
                              hipStream_t stream) {
    const float* X  = (const float*)d_in[0];
    const int*  tgt = (const int*)d_in[1];
    float* ws  = (float*)d_ws;
    float* out = (float*)d_out;

    hipLaunchKernelGGL(prep_kernel, dim3(NN / 4), dim3(256), 0, stream, X, tgt, ws);
    hipLaunchKernelGGL(negsum_kernel, dim3(NBLK), dim3(64), 0, stream, tgt, ws);
    hipLaunchKernelGGL(pair2_kernel, dim3(NCLS * NSLICE), dim3(256), 0, stream, tgt, ws, out);
}

// Round 9
// 111.633 us; speedup vs baseline: 1.1842x; 1.1842x over previous
//
#include <hip/hip_runtime.h>
#include <math.h>

#define NN 4096
#define DD 512
#define MARGINF 1.0f
#define NCLS 64
#define MAXM 160
#define TRI (MAXM * (MAXM - 1) / 2)   // 12720
#define NBLK 2080                     // 64*65/2 triangular 64-tiles
#define NSLICE 4                      // pair2 blocks per class

typedef __attribute__((ext_vector_type(8))) short bf16x8;  // 8 bf16 (4 VGPRs)
typedef __attribute__((ext_vector_type(4))) float f32x4;   // 4 fp32 acc

// ws layout (float indices):
#define WS_SQ   0         // float[4096] ||x_i||^2
#define WS_NS   4096      // float[4096] neg_sum
#define WS_LOSS 8192      // float[1] sum hinge^2
#define WS_CTR  8193      // uint[1] pair2 completion counter
#define WS_LENP 8194      // float[1] sum over classes mc*(mc-1)
#define WS_RK   8320      // int[4096] rank within class (atomic-free)
#define WS_MEM  12416     // int[64*160] class member lists (rank-indexed)
#define WS_XF   32768     // ushort[4096*512] FRAGMENT-MAJOR bf16 X (4 MB)
                          //   frag(r16,kb) = 1KB at short-off (r16*16+kb)*512;
                          //   element (q*16+m)*8+e  (q=k>>3&3, m=row&15, e=k&7)
#define WS_PD   1081344   // float[64*TRI] positive-pair distances

__device__ __forceinline__ unsigned short f2bf(float f) {
    unsigned u = __float_as_uint(f);
    u += 0x7fffu + ((u >> 16) & 1u);   // round-to-nearest-even
    return (unsigned short)(u >> 16);
}

// Row norms + fragment-major bf16 conversion + ATOMIC-FREE class ranks.
// COALESCED REWRITE (R9): the old per-lane frag store scattered 16B writes at
// ~256B stride (64 cache lines per wave-store; 262K scattered stores for 4MB).
// Now: one block per r16 group (16 rows); coalesced f32 loads -> bf16 rows in
// LDS -> frag writes as contiguous 4KB per wave. Xf BYTES ARE BIT-IDENTICAL:
// thread (f=t>>4, s=t&15) writes shorts s*32+b*8+e of frag (r16,f), which
// equals old q*128+m*8+e with q=s>>2, m=(s&3)*4+b; source element k=f*32+q*8+e.
__global__ __launch_bounds__(256) void prep_kernel(const float* __restrict__ X,
                                                   const int* __restrict__ tgt,
                                                   float* __restrict__ ws) {
    __shared__ int tg[NN];                                  // 16 KB
    __shared__ __align__(16) unsigned short rb[16][520];    // 16.25 KB (pad: 520*2=16*65)
    const int tid = threadIdx.x;
    const int r16 = blockIdx.x;                             // 256 blocks, 16 rows each
    for (int j = tid; j < NN; j += 256) tg[j] = tgt[j];

    // Phase A: 16 rows (8192 f32) coalesced load -> bf16 rows in LDS
    const float4* Xb = (const float4*)(X + (size_t)r16 * 16 * DD);
#pragma unroll
    for (int j = 0; j < 8; ++j) {
        const int v = tid + 256 * j;            // float4 index 0..2047
        float4 x = Xb[v];
        const int row = v >> 7, c4 = v & 127;   // k = c4*4 + comp
        ushort4 p = {f2bf(x.x), f2bf(x.y), f2bf(x.z), f2bf(x.w)};
        *(ushort4*)&rb[row][c4 * 4] = p;        // banks 2-way aliased: free
    }
    // Phase A2: row norms in f32 from global (coalesced, 16 threads/row)
    {
        const int row = tid >> 4, c = tid & 15;
        const float4* xr = (const float4*)(X + ((size_t)r16 * 16 + row) * DD);
        float s = 0.0f;
#pragma unroll
        for (int k = 0; k < 8; ++k) {
            float4 a = xr[c + 16 * k];
            s += a.x * a.x + a.y * a.y + a.z * a.z + a.w * a.w;
        }
        s += __shfl_xor(s, 1, 64);
        s += __shfl_xor(s, 2, 64);
        s += __shfl_xor(s, 4, 64);
        s += __shfl_xor(s, 8, 64);
        if (c == 0) {
            ws[WS_SQ + r16 * 16 + row] = s;
            ws[WS_NS + r16 * 16 + row] = 0.0f;
        }
    }
    __syncthreads();

    // Phase B: write 16 frags (16 KB contiguous) -- each wave stores 4KB
    {
        const int f = tid >> 4, s = tid & 15, q = s >> 2;
        unsigned short* dstf = (unsigned short*)(ws + WS_XF)
                               + ((size_t)(r16 * 16 + f)) * 512 + s * 32;
#pragma unroll
        for (int b = 0; b < 4; ++b) {
            const int m = (s & 3) * 4 + b;
            *(bf16x8*)(dstf + b * 8) = *(const bf16x8*)&rb[m][f * 32 + q * 8];
        }
    }

    // Phase C: class ranks for the block's 16 rows (wave wv: rows wv*4..+3)
    const int wv = tid >> 6, lane = tid & 63;
#pragma unroll
    for (int rr = 0; rr < 4; ++rr) {
        const int row = r16 * 16 + wv * 4 + rr;
        const int myc = tg[row];
        int cnt = 0;
        for (int j = lane; j < row; j += 64) cnt += (tg[j] == myc) ? 1 : 0;
#pragma unroll
        for (int off = 32; off; off >>= 1) cnt += __shfl_down(cnt, off, 64);
        if (lane == 0) {
            ((int*)(ws + WS_RK))[row] = cnt;
            if (cnt < MAXM) ((int*)(ws + WS_MEM))[myc * MAXM + cnt] = row;
        }
    }
    if (blockIdx.x == 0 && tid == 0) {
        ws[WS_LOSS] = 0.0f;
        ((unsigned*)ws)[WS_CTR] = 0u;
        ws[WS_LENP] = 0.0f;
    }
}

// Gram via bf16 MFMA — R7 EXACT (proven best: ~34 us). 64x64 tile, 2080
// XCD-swizzled blocks, wave = 32x32, LDS panel sharing (266 MB fetch),
// distance-2 counted-vmcnt schedule over a 3-buffer ring (24 KB).
__global__ __launch_bounds__(256, 6) void negsum_kernel(const int* __restrict__ tgt,
                                                        float* __restrict__ ws) {
    __shared__ unsigned short lds[3][8][512];   // [buf][frag: 0-3 A, 4-7 B] 24 KB
    // XCD-chunked bijective swizzle: 2080 = 8 * 260.
    const int bidx = (blockIdx.x & 7) * 260 + (blockIdx.x >> 3);
    int bj = (int)((sqrtf(8.0f * (float)bidx + 1.0f) - 1.0f) * 0.5f);
    while (bj * (bj + 1) / 2 > bidx) --bj;
    while ((bj + 1) * (bj + 2) / 2 <= bidx) ++bj;
    const int bi = bidx - bj * (bj + 1) / 2;   // bi <= bj
    const int i0 = bi * 64, j0 = bj * 64;

    const int tid = threadIdx.x;
    const int w = tid >> 6, lane = tid & 63;
    const int m_ = lane & 15, q = lane >> 4;
    const int wr = (w & 1) * 32, wc = (w >> 1) * 32;   // wave's 32x32 quadrant
    const unsigned short* Xf = (const unsigned short*)(ws + WS_XF);
    const int air0 = i0 >> 4, bjr0 = j0 >> 4;

    int fr16[2];
#pragma unroll
    for (int s = 0; s < 2; ++s) {
        const int f = w * 2 + s;
        fr16[s] = (f < 4) ? (air0 + f) : (bjr0 + (f - 4));
    }

#define DMA_CHUNK(kb_, buf_)                                                   \
    {                                                                          \
        _Pragma("unroll")                                                      \
        for (int s = 0; s < 2; ++s) {                                          \
            const unsigned short* gp =                                         \
                Xf + ((size_t)fr16[s] * 16 + (kb_)) * 512 + lane * 8;          \
            __builtin_amdgcn_global_load_lds(                                  \
                (const __attribute__((address_space(1))) int*)gp,              \
                (__attribute__((address_space(3))) int*)(&lds[buf_][w * 2 + s][0]), \
                16, 0, 0);                                                     \
        }                                                                      \
    }

    f32x4 acc[2][2] = {};

    DMA_CHUNK(0, 0)
    DMA_CHUNK(1, 1)
    asm volatile("s_waitcnt vmcnt(2)" ::: "memory");
    __builtin_amdgcn_s_barrier();

#pragma unroll
    for (int t = 0; t < 16; ++t) {
        const int cur = t % 3;
        if (t < 14) DMA_CHUNK(t + 2, (t + 2) % 3)
        bf16x8 af[2], bf[2];
#pragma unroll
        for (int u = 0; u < 2; ++u)
            af[u] = *(const bf16x8*)&lds[cur][(w & 1) * 2 + u][lane * 8];
#pragma unroll
        for (int v = 0; v < 2; ++v)
            bf[v] = *(const bf16x8*)&lds[cur][4 + (w >> 1) * 2 + v][lane * 8];
        acc[0][0] = __builtin_amdgcn_mfma_f32_16x16x32_bf16(af[0], bf[0], acc[0][0], 0, 0, 0);
        acc[0][1] = __builtin_amdgcn_mfma_f32_16x16x32_bf16(af[0], bf[1], acc[0][1], 0, 0, 0);
        acc[1][0] = __builtin_amdgcn_mfma_f32_16x16x32_bf16(af[1], bf[0], acc[1][0], 0, 0, 0);
        acc[1][1] = __builtin_amdgcn_mfma_f32_16x16x32_bf16(af[1], bf[1], acc[1][1], 0, 0, 0);
        if (t < 14) {
            asm volatile("s_waitcnt vmcnt(2)" ::: "memory");   // chunk t+1 ready
            __builtin_amdgcn_s_barrier();
        } else if (t == 14) {
            asm volatile("s_waitcnt vmcnt(0)" ::: "memory");   // last chunk ready
            __builtin_amdgcn_s_barrier();
        }
    }
#undef DMA_CHUNK

    // epilogue: C/D map col=lane&15, row=(lane>>4)*4+reg
    const float* sq = ws + WS_SQ;
    float* ns = ws + WS_NS;
    const int* rk = (const int*)(ws + WS_RK);
    float* posd = ws + WS_PD;
    float sjv[2]; int tjv[2], jv[2];
#pragma unroll
    for (int v = 0; v < 2; ++v) {
        int j = j0 + wc + v * 16 + m_;
        jv[v] = j;
        sjv[v] = sq[j];
        tjv[v] = tgt[j];
    }
    float colp[2] = {0.0f, 0.0f};
#pragma unroll
    for (int u = 0; u < 2; ++u) {
#pragma unroll
        for (int r = 0; r < 4; ++r) {
            const int i = i0 + wr + u * 16 + q * 4 + r;
            const float si = sq[i];
            const int ti = tgt[i];
            float rp = 0.0f;
#pragma unroll
            for (int v = 0; v < 2; ++v) {
                float d2 = si + sjv[v] - 2.0f * acc[u][v][r];
                float dist = d2 > 0.0f ? sqrtf(d2) : 0.0f;
                if (tjv[v] != ti) {
                    float e = __expf(MARGINF - dist);
                    rp += e;
                    colp[v] += e;
                } else if (i < jv[v]) {
                    int ra = rk[i], rb = rk[jv[v]];
                    if (ra < MAXM && rb < MAXM) {
                        int hi = ra > rb ? ra : rb;
                        int lo = ra > rb ? rb : ra;
                        posd[ti * TRI + hi * (hi - 1) / 2 + lo] = dist;
                    }
                }
            }
            rp += __shfl_xor(rp, 1, 64);
            rp += __shfl_xor(rp, 2, 64);
            rp += __shfl_xor(rp, 4, 64);
            rp += __shfl_xor(rp, 8, 64);
            if (m_ == 0) atomicAdd(&ns[i], rp);
        }
    }
    if (bi != bj) {   // symmetric contribution: G[j][i] == G[i][j]
#pragma unroll
        for (int v = 0; v < 2; ++v) {
            float cp = colp[v];
            cp += __shfl_xor(cp, 16, 64);
            cp += __shfl_xor(cp, 32, 64);
            if (q == 0) atomicAdd(&ns[jv[v]], cp);
        }
    }
}

// Positive pairs from stored distances; NSLICE blocks per class for occupancy;
// last block finalizes out = loss / len_p.
__global__ __launch_bounds__(256) void pair2_kernel(const int* __restrict__ tgt,
                                                    float* __restrict__ ws,
                                                    float* __restrict__ out) {
    __shared__ float wsum[4];
    __shared__ int csum[4];
    __shared__ bool last;
    const int c = blockIdx.x >> 2;
    const int sl = blockIdx.x & 3;
    const int tid = threadIdx.x;
    const int wv = tid >> 6, lane = tid & 63;

    int ccount = 0;
    for (int j = tid; j < NN; j += 256) ccount += (tgt[j] == c) ? 1 : 0;
#pragma unroll
    for (int off = 32; off; off >>= 1) ccount += __shfl_down(ccount, off, 64);
    if (lane == 0) csum[wv] = ccount;
    __syncthreads();
    int mc = csum[0] + csum[1] + csum[2] + csum[3];
    if (mc > MAXM) mc = MAXM;
    const int P = mc * (mc - 1) / 2;

    const int* mem = (const int*)(ws + WS_MEM) + c * MAXM;
    const float* pd = ws + WS_PD + c * TRI;
    const float* ns = ws + WS_NS;
    float lsum = 0.0f;
    for (int p = tid + sl * 256; p < P; p += 256 * NSLICE) {
        int b = (int)((1.0f + sqrtf(1.0f + 8.0f * (float)p)) * 0.5f);
        while (b * (b - 1) / 2 > p) --b;
        while ((b + 1) * b / 2 <= p) ++b;
        const int a = p - b * (b - 1) / 2;
        const float dist = pd[b * (b - 1) / 2 + a];
        const int i = mem[a], j = mem[b];
        float J = __logf(ns[i] + ns[j]) + dist;
        float h = fmaxf(J, 0.0f);
        lsum += h * h;
    }
#pragma unroll
    for (int off = 32; off; off >>= 1) lsum += __shfl_xor(lsum, off, 64);
    if (lane == 0) wsum[wv] = lsum;
    __syncthreads();
    if (tid == 0) {
        float s = wsum[0] + wsum[1] + wsum[2] + wsum[3];
        if (s != 0.0f) atomicAdd(&ws[WS_LOSS], s);
        if (sl == 0) atomicAdd(&ws[WS_LENP], (float)(mc * (mc - 1)));
        __threadfence();
        unsigned d = atomicAdd((unsigned*)ws + WS_CTR, 1u);
        last = (d == NCLS * NSLICE - 1);
    }
    __syncthreads();
    if (last && tid == 0) {
        float total = atomicAdd(&ws[WS_LOSS], 0.0f);   // device-scope reads
        float lp = atomicAdd(&ws[WS_LENP], 0.0f);
        out[0] = total / lp;
    }
}

extern "C" void kernel_launch(void* const* d_in, const int* in_sizes, int n_in,
                              void* d_out, int out_size, void* d_ws, size_t ws_size,
                              hipStream_t stream) {
    const float* X  = (const float*)d_in[0];
    const int*  tgt = (const int*)d_in[1];
    float* ws  = (float*)d_ws;
    float* out = (float*)d_out;

    hipLaunchKernelGGL(prep_kernel, dim3(NN / 16), dim3(256), 0, stream, X, tgt, ws);
    hipLaunchKernelGGL(negsum_kernel, dim3(NBLK), dim3(256), 0, stream, tgt, ws);
    hipLaunchKernelGGL(pair2_kernel, dim3(NCLS * NSLICE), dim3(256), 0, stream, tgt, ws, out);
}